// Round 4
// baseline (2594.520 us; speedup 1.0000x reference)
//
#include <hip/hip_runtime.h>
#include <hip/hip_bf16.h>
#include <cstdint>

typedef __bf16 bf16;
typedef __bf16 bf16x8 __attribute__((ext_vector_type(8)));
typedef float f32x4 __attribute__((ext_vector_type(4)));
typedef unsigned int u32x4 __attribute__((ext_vector_type(4)));

#define B_ 4
#define S_ 2048
#define D_ 2048
#define H_ 16
#define NOPE_ 128
#define ROPE_ 64
#define V_ 128
#define KVR_ 512
#define QK_ 192
#define KD_ 576   // KVR + ROPE

__device__ __forceinline__ bf16 tobf(float f) {
  unsigned u = __float_as_uint(f);
  u += 0x7fffu + ((u >> 16) & 1u);          // RNE
  unsigned short s = (unsigned short)(u >> 16);
  return *reinterpret_cast<bf16*>(&s);
}
__device__ __forceinline__ float tof(bf16 v) {
  unsigned short s = *reinterpret_cast<unsigned short*>(&v);
  return __uint_as_float(((unsigned)s) << 16);
}

// ---------------- elementwise: f32 -> bf16 cast (8 elems/thread) ----------------
__global__ void cast_bf16(const float* __restrict__ in, bf16* __restrict__ out, long n) {
  long i = ((long)blockIdx.x * 256 + threadIdx.x) * 8;
  if (i >= n) return;
  float4 a = *(const float4*)(in + i);
  float4 b = *(const float4*)(in + i + 4);
  bf16x8 v;
  v[0] = tobf(a.x); v[1] = tobf(a.y); v[2] = tobf(a.z); v[3] = tobf(a.w);
  v[4] = tobf(b.x); v[5] = tobf(b.y); v[6] = tobf(b.z); v[7] = tobf(b.w);
  *(bf16x8*)(out + i) = v;
}

// ---------------- wkv_b prep ----------------
__global__ void prep_wkvb(const float* __restrict__ w, bf16* __restrict__ wnT, bf16* __restrict__ wv) {
  int tid = blockIdx.x * 256 + threadIdx.x;
  {
    int c = tid & 511, rest = tid >> 9, d = rest & 127, h = rest >> 7;
    wv[tid] = tobf(w[((long)(h * 256 + 128 + d) << 9) + c]);
  }
  {
    int d = tid & 127, rest = tid >> 7, c = rest & 511, h = rest >> 9;
    wnT[tid] = tobf(w[((long)(h * 256 + d) << 9) + c]);
  }
}

// ---------------- generic BT GEMM ----------------
template <typename OutT>
__global__ __launch_bounds__(256)
void gemm_bt(const bf16* __restrict__ A, long lda, long aOffZ,
             const bf16* __restrict__ Bm, long ldb, long bOffZ,
             OutT* __restrict__ C, long ldc, long cOffZ,
             int M, int N, int K)
{
  A += aOffZ * blockIdx.z;
  Bm += bOffZ * blockIdx.z;
  C += cOffZ * blockIdx.z;
  const int m0 = blockIdx.y * 128, n0 = blockIdx.x * 128;
  const int tid = threadIdx.x;
  const int wave = tid >> 6, lane = tid & 63, quad = lane >> 4, r = lane & 15;
  const int wm = (wave >> 1) * 64, wn = (wave & 1) * 64;
  __shared__ __align__(16) bf16 As[128][40];
  __shared__ __align__(16) bf16 Bs[128][40];
  f32x4 acc[4][4] = {};
  for (int k0 = 0; k0 < K; k0 += 32) {
    __syncthreads();
#pragma unroll
    for (int it = 0; it < 2; ++it) {
      int idx = tid + it * 256;
      int row = idx >> 2, ch = (idx & 3) * 8;
      long ar = m0 + row; if (ar > (long)M - 1) ar = M - 1;
      *(u32x4*)&As[row][ch] = *(const u32x4*)(A + ar * lda + k0 + ch);
      long br = n0 + row; if (br > (long)N - 1) br = N - 1;
      *(u32x4*)&Bs[row][ch] = *(const u32x4*)(Bm + br * ldb + k0 + ch);
    }
    __syncthreads();
    bf16x8 af[4], bfr[4];
#pragma unroll
    for (int i = 0; i < 4; ++i) af[i] = *(const bf16x8*)&As[wm + i * 16 + r][quad * 8];
#pragma unroll
    for (int j = 0; j < 4; ++j) bfr[j] = *(const bf16x8*)&Bs[wn + j * 16 + r][quad * 8];
#pragma unroll
    for (int i = 0; i < 4; ++i)
#pragma unroll
      for (int j = 0; j < 4; ++j)
        acc[i][j] = __builtin_amdgcn_mfma_f32_16x16x32_bf16(af[i], bfr[j], acc[i][j], 0, 0, 0);
  }
#pragma unroll
  for (int i = 0; i < 4; ++i) {
    int mrow = m0 + wm + i * 16 + quad * 4;
#pragma unroll
    for (int j = 0; j < 4; ++j) {
      int ncol = n0 + wn + j * 16 + r;
      if (ncol < N) {
#pragma unroll
        for (int t = 0; t < 4; ++t) {
          if (mrow + t < M) {
            if constexpr (__is_same(OutT, float))
              C[(long)(mrow + t) * ldc + ncol] = acc[i][j][t];
            else
              C[(long)(mrow + t) * ldc + ncol] = tobf(acc[i][j][t]);
          }
        }
      }
    }
  }
}

// ---------------- kv rmsnorm + rope(k_pe) -> Keff (T,576) bf16, per batch ----------------
__global__ void kv_norm(const float* __restrict__ kvf, const float* __restrict__ w,
                        const float* __restrict__ fcos, const float* __restrict__ fsin,
                        bf16* __restrict__ keff) {
  int row = blockIdx.x * 4 + (threadIdx.x >> 6);
  int lane = threadIdx.x & 63;
  int t = row;
  const float* src = kvf + (long)row * KD_;
  float v[8]; float ss = 0.f;
#pragma unroll
  for (int i = 0; i < 8; ++i) { v[i] = src[lane * 8 + i]; ss += v[i] * v[i]; }
#pragma unroll
  for (int off = 1; off < 64; off <<= 1) ss += __shfl_xor(ss, off, 64);
  float rms = rsqrtf(ss * (1.f / 512.f) + 1e-6f);
  bf16* dst = keff + (long)row * KD_;
#pragma unroll
  for (int i = 0; i < 8; ++i) dst[lane * 8 + i] = tobf(v[i] * rms * w[lane * 8 + i]);
  if (lane < 32) {
    float x1 = src[KVR_ + 2 * lane], x2 = src[KVR_ + 2 * lane + 1];
    float c = fcos[t * 32 + lane], s = fsin[t * 32 + lane];
    dst[KVR_ + 2 * lane]     = tobf(x1 * c - x2 * s);
    dst[KVR_ + 2 * lane + 1] = tobf(x1 * s + x2 * c);
  }
}

// ---------------- kv_c transpose -> kvcT (512,T), per batch ----------------
__global__ void transpose_kvc(const bf16* __restrict__ keff, bf16* __restrict__ kvcT) {
  int c0 = blockIdx.y * 32, t0 = blockIdx.x * 32;
  __shared__ bf16 tile[32][33];
  int x = threadIdx.x & 31, y = threadIdx.x >> 5;
#pragma unroll
  for (int k = 0; k < 4; ++k) {
    int t = t0 + y + k * 8;
    tile[y + k * 8][x] = keff[(long)t * KD_ + c0 + x];
  }
  __syncthreads();
#pragma unroll
  for (int k = 0; k < 4; ++k) {
    int c = c0 + y + k * 8;
    kvcT[(long)c * S_ + t0 + x] = tile[x][y + k * 8];
  }
}

// ---------------- q rope -> qeff[...,512:576], per batch ----------------
__global__ void rope_q(const bf16* __restrict__ qb, const float* __restrict__ fcos,
                       const float* __restrict__ fsin, bf16* __restrict__ qeff) {
  long tid = (long)blockIdx.x * 256 + threadIdx.x;
  int i = tid & 31; int h = (tid >> 5) & 15; long bs = tid >> 9; int t = (int)bs;
  const bf16* src = qb + bs * (H_ * QK_) + h * QK_ + NOPE_ + 2 * i;
  float x1 = tof(src[0]), x2 = tof(src[1]);
  float c = fcos[t * 32 + i], s = fsin[t * 32 + i];
  long o = (bs * H_ + h) * KD_ + KVR_ + 2 * i;
  qeff[o]     = tobf(x1 * c - x2 * s);
  qeff[o + 1] = tobf(x1 * s + x2 * c);
}

// ---------------- flash attention v3 (per batch) ----------------
// Block = 4 waves, 64 q-rows, one head. blockIdx.x: qt = 31-(bx>>4) (big blocks first), h = bx&15.
// QK^T: wave w owns queries 16w..16w+15; S^T = mfma(A=K-frag, B=Q-regs) -> D[key][query]:
//   per-lane scalar m/l (query = lane&15), softmax reduce = 7 VALU + 2 shuffles.
// P^T -> LDS Pl[64 queries][32 keys]; alpha/linv broadcast via tiny LDS arrays.
// PV: wave (rh=w&1, ch=w>>1) owns rows 32rh..+32, cols 256ch..+256; 16x16x32, acc 128 VGPR.
__global__ __launch_bounds__(256, 2)
void flash_mla(const bf16* __restrict__ Qeff, const bf16* __restrict__ Keff,
               const bf16* __restrict__ kvcT, bf16* __restrict__ Oc)
{
  const int qt = 31 - (blockIdx.x >> 4);
  const int h = blockIdx.x & 15;
  const int s0 = qt * 64;
  const int tid = threadIdx.x;
  const int wave = tid >> 6, lane = tid & 63, quad = lane >> 4, r = lane & 15;
  const int rh = wave & 1, ch = wave >> 1;
  const int nt = 2 * qt + 2;

  __shared__ __align__(16) bf16 Ks[32][584];      // 37,376 B
  __shared__ __align__(16) bf16 Vs[512][36];      // 36,864 B
  __shared__ __align__(16) bf16 Pl[64][36];       //  4,608 B
  __shared__ __align__(16) float alphaL[64];      //    256 B
  __shared__ __align__(16) float linvL[64];       //    256 B
  const float scale = 0.07216878364870323f;       // 1/sqrt(192)

  // Q fragments in registers: this wave's 16 queries (s0+16w .. +16), all 576 k
  const int qrow = s0 + 16 * wave + r;            // absolute query row for lane
  bf16x8 aq[18];
  const bf16* qptr = Qeff + ((long)qrow * H_ + h) * KD_;
#pragma unroll
  for (int kc = 0; kc < 18; ++kc) aq[kc] = *(const bf16x8*)(qptr + kc * 32 + quad * 8);

  f32x4 o0[16] = {};   // rows 32rh + quad*4..+4   x cols 256ch+16j+r
  f32x4 o1[16] = {};   // rows 32rh+16 + quad*4..+4
  float m_run = -INFINITY, l_run = 0.f;

  for (int kt = 0; kt < nt; ++kt) {
    const int t0 = kt * 32;
    __syncthreads();                               // prev PV done: Ks/Vs/Pl/alphaL reusable
    // stage K tile 32x576
#pragma unroll
    for (int i = 0; i < 9; ++i) {
      int c = tid + i * 256;
      int row = c / 72, col = c - row * 72;
      *(u32x4*)&Ks[row][col * 8] = *(const u32x4*)(Keff + (long)(t0 + row) * KD_ + col * 8);
    }
    // stage V tile 512x32
#pragma unroll
    for (int i = 0; i < 8; ++i) {
      int c = tid + i * 256;
      int row = c >> 2, col = c & 3;
      *(u32x4*)&Vs[row][col * 8] = *(const u32x4*)(kvcT + (long)row * S_ + t0 + col * 8);
    }
    __syncthreads();
    // S^T = K @ Q^T for this wave's 16 queries: D[key][query=lane&15]
    f32x4 sacc0 = {}, sacc1 = {};
#pragma unroll
    for (int kc = 0; kc < 18; ++kc) {
      bf16x8 k0 = *(const bf16x8*)&Ks[r][kc * 32 + quad * 8];
      bf16x8 k1 = *(const bf16x8*)&Ks[16 + r][kc * 32 + quad * 8];
      sacc0 = __builtin_amdgcn_mfma_f32_16x16x32_bf16(k0, aq[kc], sacc0, 0, 0, 0);
      sacc1 = __builtin_amdgcn_mfma_f32_16x16x32_bf16(k1, aq[kc], sacc1, 0, 0, 0);
    }
    // scale + causal mask; keys = t0 + 16ns + quad*4 + tt
    float s8[8];
#pragma unroll
    for (int tt = 0; tt < 4; ++tt) {
      int ka = t0 + quad * 4 + tt;
      s8[tt]     = (ka      <= qrow) ? sacc0[tt] * scale : -INFINITY;
      s8[4 + tt] = (ka + 16 <= qrow) ? sacc1[tt] * scale : -INFINITY;
    }
    float mx = s8[0];
#pragma unroll
    for (int i = 1; i < 8; ++i) mx = fmaxf(mx, s8[i]);
    mx = fmaxf(mx, __shfl_xor(mx, 16, 64));
    mx = fmaxf(mx, __shfl_xor(mx, 32, 64));
    float mnew = fmaxf(m_run, mx);
    float alpha = __expf(m_run - mnew);
    float ps = 0.f;
#pragma unroll
    for (int i = 0; i < 8; ++i) { float pv = __expf(s8[i] - mnew); s8[i] = pv; ps += pv; }
    ps += __shfl_xor(ps, 16, 64);
    ps += __shfl_xor(ps, 32, 64);
    l_run = l_run * alpha + ps;
    m_run = mnew;
    // write P^T (A-operand layout for PV): Pl[query][key]
#pragma unroll
    for (int tt = 0; tt < 4; ++tt) {
      Pl[16 * wave + r][quad * 4 + tt]      = tobf(s8[tt]);
      Pl[16 * wave + r][16 + quad * 4 + tt] = tobf(s8[4 + tt]);
    }
    if (quad == 0) alphaL[16 * wave + r] = alpha;
    __syncthreads();                               // P/alpha visible
    // rescale accumulators (alpha per absolute row, broadcast from LDS)
    f32x4 a0 = *(const f32x4*)&alphaL[32 * rh + quad * 4];
    f32x4 a1 = *(const f32x4*)&alphaL[32 * rh + 16 + quad * 4];
#pragma unroll
    for (int j = 0; j < 16; ++j) {
#pragma unroll
      for (int tt = 0; tt < 4; ++tt) { o0[j][tt] *= a0[tt]; o1[j][tt] *= a1[tt]; }
    }
    // PV: o[32 rows x 256 cols] += P(32x32) @ V(32x256)
    bf16x8 p0 = *(const bf16x8*)&Pl[32 * rh + r][quad * 8];
    bf16x8 p1 = *(const bf16x8*)&Pl[32 * rh + 16 + r][quad * 8];
#pragma unroll
    for (int j = 0; j < 16; ++j) {
      bf16x8 bv = *(const bf16x8*)&Vs[256 * ch + 16 * j + r][quad * 8];
      o0[j] = __builtin_amdgcn_mfma_f32_16x16x32_bf16(p0, bv, o0[j], 0, 0, 0);
      o1[j] = __builtin_amdgcn_mfma_f32_16x16x32_bf16(p1, bv, o1[j], 0, 0, 0);
    }
  }
  // epilogue
  if (quad == 0) linvL[16 * wave + r] = 1.0f / l_run;
  __syncthreads();
  f32x4 li0 = *(const f32x4*)&linvL[32 * rh + quad * 4];
  f32x4 li1 = *(const f32x4*)&linvL[32 * rh + 16 + quad * 4];
#pragma unroll
  for (int tt = 0; tt < 4; ++tt) {
    long row0 = (long)(s0 + 32 * rh + quad * 4 + tt);
    long row1 = row0 + 16;
    bf16* orow0 = Oc + (row0 * H_ + h) * KVR_ + 256 * ch;
    bf16* orow1 = Oc + (row1 * H_ + h) * KVR_ + 256 * ch;
#pragma unroll
    for (int j = 0; j < 16; ++j) {
      orow0[j * 16 + r] = tobf(o0[j][tt] * li0[tt]);
      orow1[j * 16 + r] = tobf(o1[j][tt] * li1[tt]);
    }
  }
}

extern "C" void kernel_launch(void* const* d_in, const int* in_sizes, int n_in,
                              void* d_out, int out_size, void* d_ws, size_t ws_size,
                              hipStream_t stream) {
  (void)in_sizes; (void)n_in; (void)out_size; (void)ws_size;
  const float* x     = (const float*)d_in[0];
  const float* wq    = (const float*)d_in[1];
  const float* wkv_a = (const float*)d_in[2];
  const float* kvw   = (const float*)d_in[3];
  const float* wkv_b = (const float*)d_in[4];
  const float* wo    = (const float*)d_in[5];
  const float* fcos  = (const float*)d_in[6];
  const float* fsin  = (const float*)d_in[7];
  float* out = (float*)d_out;

  char* p = (char*)d_ws;
  auto alloc = [&](size_t bytes) { char* q = p; p += (bytes + 255) & ~(size_t)255; return q; };
  const long MR = (long)B_ * S_;
  bf16* xb   = (bf16*)alloc(MR * D_ * 2);
  bf16* out2 = (bf16*)alloc(MR * D_ * 2);
  bf16* wqb  = (bf16*)alloc((long)H_ * QK_ * D_ * 2);
  bf16* wab  = (bf16*)alloc((long)KD_ * D_ * 2);
  bf16* wob  = (bf16*)alloc((long)D_ * D_ * 2);
  bf16* wbnT = (bf16*)alloc((long)H_ * KVR_ * NOPE_ * 2);
  bf16* wbv  = (bf16*)alloc((long)H_ * V_ * KVR_ * 2);
  float* kvf = (float*)alloc((long)S_ * KD_ * 4);
  bf16* keff = (bf16*)alloc((long)S_ * KD_ * 2);
  bf16* kvcT = (bf16*)alloc((long)KVR_ * S_ * 2);
  bf16* qb   = (bf16*)alloc((long)S_ * H_ * QK_ * 2);
  bf16* qeff = (bf16*)alloc((long)S_ * H_ * KD_ * 2);
  bf16* oc   = (bf16*)alloc((long)S_ * H_ * KVR_ * 2);

  cast_bf16<<<(MR * D_) >> 11, 256, 0, stream>>>(x, xb, MR * D_);
  cast_bf16<<<((long)H_ * QK_ * D_) >> 11, 256, 0, stream>>>(wq, wqb, (long)H_ * QK_ * D_);
  cast_bf16<<<((long)KD_ * D_) >> 11, 256, 0, stream>>>(wkv_a, wab, (long)KD_ * D_);
  cast_bf16<<<((long)D_ * D_) >> 11, 256, 0, stream>>>(wo, wob, (long)D_ * D_);
  prep_wkvb<<<4096, 256, 0, stream>>>(wkv_b, wbnT, wbv);

  for (int b = 0; b < B_; ++b) {
    const bf16* xb_b = xb + (long)b * S_ * D_;
    bf16* out2_b = out2 + (long)b * S_ * D_;
    gemm_bt<float><<<dim3(5, 16, 1), 256, 0, stream>>>(xb_b, D_, 0, wab, D_, 0,
                                                       kvf, KD_, 0, S_, KD_, D_);
    kv_norm<<<S_ / 4, 256, 0, stream>>>(kvf, kvw, fcos, fsin, keff);
    transpose_kvc<<<dim3(S_ / 32, KVR_ / 32, 1), 256, 0, stream>>>(keff, kvcT);
    gemm_bt<bf16><<<dim3(24, 16, 1), 256, 0, stream>>>(xb_b, D_, 0, wqb, D_, 0,
                                                       qb, H_ * QK_, 0, S_, H_ * QK_, D_);
    rope_q<<<(S_ * H_ * 32) / 256, 256, 0, stream>>>(qb, fcos, fsin, qeff);
    gemm_bt<bf16><<<dim3(4, 16, H_), 256, 0, stream>>>(qb, H_ * QK_, QK_,
                                                       wbnT, NOPE_, (long)KVR_ * NOPE_,
                                                       qeff, H_ * KD_, KD_, S_, KVR_, NOPE_);
    flash_mla<<<dim3(512), 256, 0, stream>>>(qeff, keff, kvcT, oc);
    gemm_bt<bf16><<<dim3(1, 16, H_), 256, 0, stream>>>(oc, H_ * KVR_, KVR_,
                                                       wbv, KVR_, (long)V_ * KVR_,
                                                       out2_b, D_, V_, S_, V_, KVR_);
  }
  gemm_bt<float><<<dim3(16, 64, 1), 256, 0, stream>>>(out2, D_, 0, wob, D_, 0,
                                                      out, D_, 0, MR, D_, D_);
}

// Round 5
// 2563.924 us; speedup vs baseline: 1.0119x; 1.0119x over previous
//
#include <hip/hip_runtime.h>
#include <hip/hip_bf16.h>
#include <cstdint>

typedef __bf16 bf16;
typedef __bf16 bf16x8 __attribute__((ext_vector_type(8)));
typedef __bf16 bf16x4 __attribute__((ext_vector_type(4)));
typedef float f32x4 __attribute__((ext_vector_type(4)));
typedef unsigned int u32x4 __attribute__((ext_vector_type(4)));

#define B_ 4
#define S_ 2048
#define D_ 2048
#define H_ 16
#define NOPE_ 128
#define ROPE_ 64
#define V_ 128
#define KVR_ 512
#define QK_ 192
#define KD_ 576   // KVR + ROPE

#define LDS_AS __attribute__((address_space(3)))
#define GLB_AS __attribute__((address_space(1)))

__device__ __forceinline__ void async16(const bf16* g, bf16* l) {
  __builtin_amdgcn_global_load_lds((const GLB_AS uint32_t*)g, (LDS_AS uint32_t*)l, 16, 0, 0);
}

__device__ __forceinline__ bf16 tobf(float f) {
  unsigned u = __float_as_uint(f);
  u += 0x7fffu + ((u >> 16) & 1u);          // RNE
  unsigned short s = (unsigned short)(u >> 16);
  return *reinterpret_cast<bf16*>(&s);
}
__device__ __forceinline__ float tof(bf16 v) {
  unsigned short s = *reinterpret_cast<unsigned short*>(&v);
  return __uint_as_float(((unsigned)s) << 16);
}

// ---------------- elementwise: f32 -> bf16 cast ----------------
__global__ void cast_bf16(const float* __restrict__ in, bf16* __restrict__ out, long n) {
  long i = ((long)blockIdx.x * 256 + threadIdx.x) * 8;
  if (i >= n) return;
  float4 a = *(const float4*)(in + i);
  float4 b = *(const float4*)(in + i + 4);
  bf16x8 v;
  v[0] = tobf(a.x); v[1] = tobf(a.y); v[2] = tobf(a.z); v[3] = tobf(a.w);
  v[4] = tobf(b.x); v[5] = tobf(b.y); v[6] = tobf(b.z); v[7] = tobf(b.w);
  *(bf16x8*)(out + i) = v;
}

// ---------------- wkv_b prep ----------------
__global__ void prep_wkvb(const float* __restrict__ w, bf16* __restrict__ wnT, bf16* __restrict__ wv) {
  int tid = blockIdx.x * 256 + threadIdx.x;
  {
    int c = tid & 511, rest = tid >> 9, d = rest & 127, h = rest >> 7;
    wv[tid] = tobf(w[((long)(h * 256 + 128 + d) << 9) + c]);
  }
  {
    int d = tid & 127, rest = tid >> 7, c = rest & 511, h = rest >> 9;
    wnT[tid] = tobf(w[((long)(h * 256 + d) << 9) + c]);
  }
}

// ---------------- generic BT GEMM ----------------
template <typename OutT>
__global__ __launch_bounds__(256)
void gemm_bt(const bf16* __restrict__ A, long lda, long aOffZ,
             const bf16* __restrict__ Bm, long ldb, long bOffZ,
             OutT* __restrict__ C, long ldc, long cOffZ,
             int M, int N, int K)
{
  A += aOffZ * blockIdx.z;
  Bm += bOffZ * blockIdx.z;
  C += cOffZ * blockIdx.z;
  const int m0 = blockIdx.y * 128, n0 = blockIdx.x * 128;
  const int tid = threadIdx.x;
  const int wave = tid >> 6, lane = tid & 63, quad = lane >> 4, r = lane & 15;
  const int wm = (wave >> 1) * 64, wn = (wave & 1) * 64;
  __shared__ __align__(16) bf16 As[128][40];
  __shared__ __align__(16) bf16 Bs[128][40];
  f32x4 acc[4][4] = {};
  for (int k0 = 0; k0 < K; k0 += 32) {
    __syncthreads();
#pragma unroll
    for (int it = 0; it < 2; ++it) {
      int idx = tid + it * 256;
      int row = idx >> 2, ch = (idx & 3) * 8;
      long ar = m0 + row; if (ar > (long)M - 1) ar = M - 1;
      *(u32x4*)&As[row][ch] = *(const u32x4*)(A + ar * lda + k0 + ch);
      long br = n0 + row; if (br > (long)N - 1) br = N - 1;
      *(u32x4*)&Bs[row][ch] = *(const u32x4*)(Bm + br * ldb + k0 + ch);
    }
    __syncthreads();
    bf16x8 af[4], bfr[4];
#pragma unroll
    for (int i = 0; i < 4; ++i) af[i] = *(const bf16x8*)&As[wm + i * 16 + r][quad * 8];
#pragma unroll
    for (int j = 0; j < 4; ++j) bfr[j] = *(const bf16x8*)&Bs[wn + j * 16 + r][quad * 8];
#pragma unroll
    for (int i = 0; i < 4; ++i)
#pragma unroll
      for (int j = 0; j < 4; ++j)
        acc[i][j] = __builtin_amdgcn_mfma_f32_16x16x32_bf16(af[i], bfr[j], acc[i][j], 0, 0, 0);
  }
#pragma unroll
  for (int i = 0; i < 4; ++i) {
    int mrow = m0 + wm + i * 16 + quad * 4;
#pragma unroll
    for (int j = 0; j < 4; ++j) {
      int ncol = n0 + wn + j * 16 + r;
      if (ncol < N) {
#pragma unroll
        for (int t = 0; t < 4; ++t) {
          if (mrow + t < M) {
            if constexpr (__is_same(OutT, float))
              C[(long)(mrow + t) * ldc + ncol] = acc[i][j][t];
            else
              C[(long)(mrow + t) * ldc + ncol] = tobf(acc[i][j][t]);
          }
        }
      }
    }
  }
}

// ---------------- kv rmsnorm + rope(k_pe) -> Keff (T,576) bf16, per batch ----------------
__global__ void kv_norm(const float* __restrict__ kvf, const float* __restrict__ w,
                        const float* __restrict__ fcos, const float* __restrict__ fsin,
                        bf16* __restrict__ keff) {
  int row = blockIdx.x * 4 + (threadIdx.x >> 6);
  int lane = threadIdx.x & 63;
  int t = row;
  const float* src = kvf + (long)row * KD_;
  float v[8]; float ss = 0.f;
#pragma unroll
  for (int i = 0; i < 8; ++i) { v[i] = src[lane * 8 + i]; ss += v[i] * v[i]; }
#pragma unroll
  for (int off = 1; off < 64; off <<= 1) ss += __shfl_xor(ss, off, 64);
  float rms = rsqrtf(ss * (1.f / 512.f) + 1e-6f);
  bf16* dst = keff + (long)row * KD_;
#pragma unroll
  for (int i = 0; i < 8; ++i) dst[lane * 8 + i] = tobf(v[i] * rms * w[lane * 8 + i]);
  if (lane < 32) {
    float x1 = src[KVR_ + 2 * lane], x2 = src[KVR_ + 2 * lane + 1];
    float c = fcos[t * 32 + lane], s = fsin[t * 32 + lane];
    dst[KVR_ + 2 * lane]     = tobf(x1 * c - x2 * s);
    dst[KVR_ + 2 * lane + 1] = tobf(x1 * s + x2 * c);
  }
}

// ---------------- kv_c transpose -> kvcT (512,T), per batch ----------------
__global__ void transpose_kvc(const bf16* __restrict__ keff, bf16* __restrict__ kvcT) {
  int c0 = blockIdx.y * 32, t0 = blockIdx.x * 32;
  __shared__ bf16 tile[32][33];
  int x = threadIdx.x & 31, y = threadIdx.x >> 5;
#pragma unroll
  for (int k = 0; k < 4; ++k) {
    int t = t0 + y + k * 8;
    tile[y + k * 8][x] = keff[(long)t * KD_ + c0 + x];
  }
  __syncthreads();
#pragma unroll
  for (int k = 0; k < 4; ++k) {
    int c = c0 + y + k * 8;
    kvcT[(long)c * S_ + t0 + x] = tile[x][y + k * 8];
  }
}

// ---------------- q rope -> qeff[...,512:576], per batch ----------------
__global__ void rope_q(const bf16* __restrict__ qb, const float* __restrict__ fcos,
                       const float* __restrict__ fsin, bf16* __restrict__ qeff) {
  long tid = (long)blockIdx.x * 256 + threadIdx.x;
  int i = tid & 31; int h = (tid >> 5) & 15; long bs = tid >> 9; int t = (int)bs;
  const bf16* src = qb + bs * (H_ * QK_) + h * QK_ + NOPE_ + 2 * i;
  float x1 = tof(src[0]), x2 = tof(src[1]);
  float c = fcos[t * 32 + i], s = fsin[t * 32 + i];
  long o = (bs * H_ + h) * KD_ + KVR_ + 2 * i;
  qeff[o]     = tobf(x1 * c - x2 * s);
  qeff[o + 1] = tobf(x1 * s + x2 * c);
}

// ---------------- flash attention v4 (per batch) ----------------
// Block = 8 waves (512 thr), 128 q-rows, 1 head. Grid 256 = 16h x 16qt, qt descending.
// Wave w: QK for queries 16w..+16 (S^T = mfma(K-frag, Q-regs), per-lane softmax m/l);
// PV: wave (rw=w&3, cw=w>>2) owns q-rows 32rw..+32 x V-cols 256cw..+256.
// K tile (32x576): double-buffered LDS, XOR-swizzled chunks, filled by
// global_load_lds(16B); prefetch for tile k+1 issued at mid-barrier of tile k
// (flight = PV phase, so barrier vmcnt drains find it complete).
// V tile (512x32 of kvcT): global->reg at mid-barrier of k-1, reg->LDS (stride 40)
// at top of tile k. P^T via LDS Pl (stride 40), alpha/linv via tiny LDS arrays.
__global__ __launch_bounds__(512, 2)
void flash_mla(const bf16* __restrict__ Qeff, const bf16* __restrict__ Keff,
               const bf16* __restrict__ kvcT, bf16* __restrict__ Oc)
{
  const int qt = 15 - (blockIdx.x >> 4);
  const int h  = blockIdx.x & 15;
  const int s0 = qt * 128;
  const int tid = threadIdx.x;
  const int wave = tid >> 6, lane = tid & 63, quad = lane >> 4, r = lane & 15;
  const int rw = wave & 3, cw = wave >> 2;
  const int nt = 4 * qt + 4;

  __shared__ __align__(16) bf16 Ks[2][32 * 576];   // 73,728 B (swizzled, unpadded)
  __shared__ __align__(16) bf16 Vs[512 * 40];      // 40,960 B (padded stride 40)
  __shared__ __align__(16) bf16 Pl[128 * 40];      // 10,240 B
  __shared__ float alphaL[128];
  __shared__ float linvL[128];

  // staging offsets (tile-invariant): Ks chunk n -> row=n/72, p=n%72, src = p ^ sK(row)
  int koffE[5];
#pragma unroll
  for (int i = 0; i < 5; ++i) {
    int n = (i < 4) ? (i * 512 + tid) : (2048 + (tid & 255));
    int row = n / 72, p = n - row * 72;
    int src = p ^ ((row ^ (row >> 3)) & 7);
    koffE[i] = row * KD_ + src * 8;
  }
  int voffG[4], voffL[4];
#pragma unroll
  for (int i = 0; i < 4; ++i) {
    int n = i * 512 + tid;
    int row = n >> 2, col = (n & 3) * 8;
    voffG[i] = row * S_ + col;
    voffL[i] = row * 40 + col;
  }

  // Q fragments: wave's 16 queries, full 576 features
  bf16x8 aq[18];
  {
    const bf16* qptr = Qeff + ((long)(s0 + 16 * wave + r) * H_ + h) * KD_;
#pragma unroll
    for (int kc = 0; kc < 18; ++kc) aq[kc] = *(const bf16x8*)(qptr + kc * 32 + quad * 8);
  }

  const int sA = (r ^ (r >> 3)) & 7;
  const int rB = 16 + r;
  const int sB = (rB ^ (rB >> 3)) & 7;
  const int qrow = s0 + 16 * wave + r;
  const float scale = 0.07216878364870323f;   // 1/sqrt(192)

  f32x4 o0[16] = {}, o1[16] = {};
  float m_run = -INFINITY, l_run = 0.f;

  // prologue: prefetch K tile 0 (async) + V tile 0 (regs)
#pragma unroll
  for (int i = 0; i < 4; ++i)
    async16(Keff + koffE[i], (bf16*)&Ks[0][(i * 512 + wave * 64) * 8]);
  if (wave < 4)
    async16(Keff + koffE[4], (bf16*)&Ks[0][(2048 + wave * 64) * 8]);
  u32x4 vreg[4];
#pragma unroll
  for (int i = 0; i < 4; ++i) vreg[i] = *(const u32x4*)(kvcT + voffG[i]);

  for (int kt = 0; kt < nt; ++kt) {
    const int t0 = kt * 32;
    const int cur = kt & 1;
    __syncthreads();   // drains K prefetch(kt) + vreg loads; prev PV done with Vs
    // V regs -> LDS (visible to all at mid-barrier)
#pragma unroll
    for (int i = 0; i < 4; ++i) *(u32x4*)&Vs[voffL[i]] = vreg[i];
    // QK on Ks[cur]: S^T, D[key][query=lane&15]
    f32x4 sacc0 = {}, sacc1 = {};
#pragma unroll
    for (int kc = 0; kc < 18; ++kc) {
      bf16x8 k0 = *(const bf16x8*)&Ks[cur][(r  * 72 + ((4 * kc + quad) ^ sA)) * 8];
      bf16x8 k1 = *(const bf16x8*)&Ks[cur][(rB * 72 + ((4 * kc + quad) ^ sB)) * 8];
      sacc0 = __builtin_amdgcn_mfma_f32_16x16x32_bf16(k0, aq[kc], sacc0, 0, 0, 0);
      sacc1 = __builtin_amdgcn_mfma_f32_16x16x32_bf16(k1, aq[kc], sacc1, 0, 0, 0);
    }
    // online softmax (query = qrow at every lane; keys t0+quad*4+tt, +16)
    float s8[8];
#pragma unroll
    for (int tt = 0; tt < 4; ++tt) {
      int ka = t0 + quad * 4 + tt;
      s8[tt]     = (ka      <= qrow) ? sacc0[tt] * scale : -INFINITY;
      s8[4 + tt] = (ka + 16 <= qrow) ? sacc1[tt] * scale : -INFINITY;
    }
    float mx = s8[0];
#pragma unroll
    for (int i = 1; i < 8; ++i) mx = fmaxf(mx, s8[i]);
    mx = fmaxf(mx, __shfl_xor(mx, 16, 64));
    mx = fmaxf(mx, __shfl_xor(mx, 32, 64));
    float mnew = fmaxf(m_run, mx);
    float alpha = __expf(m_run - mnew);
    float ps = 0.f;
#pragma unroll
    for (int i = 0; i < 8; ++i) { float pv = __expf(s8[i] - mnew); s8[i] = pv; ps += pv; }
    ps += __shfl_xor(ps, 16, 64);
    ps += __shfl_xor(ps, 32, 64);
    l_run = l_run * alpha + ps;
    m_run = mnew;
    // write P^T: Pl[query 16w+r][key]
    {
      bf16x4 plo, phi;
#pragma unroll
      for (int tt = 0; tt < 4; ++tt) { plo[tt] = tobf(s8[tt]); phi[tt] = tobf(s8[4 + tt]); }
      *(bf16x4*)&Pl[(16 * wave + r) * 40 + quad * 4]      = plo;
      *(bf16x4*)&Pl[(16 * wave + r) * 40 + 16 + quad * 4] = phi;
    }
    if (quad == 0) alphaL[16 * wave + r] = alpha;
    __syncthreads();   // Pl/alpha/Vs visible; no vm loads pending -> cheap drain
    // prefetch tile kt+1: K async into other buffer, V into regs (flight = PV phase)
    if (kt + 1 < nt) {
      const bf16* kb = Keff + (long)(t0 + 32) * KD_;
#pragma unroll
      for (int i = 0; i < 4; ++i)
        async16(kb + koffE[i], (bf16*)&Ks[1 - cur][(i * 512 + wave * 64) * 8]);
      if (wave < 4)
        async16(kb + koffE[4], (bf16*)&Ks[1 - cur][(2048 + wave * 64) * 8]);
      const bf16* vb = kvcT + t0 + 32;
#pragma unroll
      for (int i = 0; i < 4; ++i) vreg[i] = *(const u32x4*)(vb + voffG[i]);
    }
    // rescale accumulators
    f32x4 a0 = *(const f32x4*)&alphaL[32 * rw + quad * 4];
    f32x4 a1 = *(const f32x4*)&alphaL[32 * rw + 16 + quad * 4];
#pragma unroll
    for (int j = 0; j < 16; ++j) {
#pragma unroll
      for (int tt = 0; tt < 4; ++tt) { o0[j][tt] *= a0[tt]; o1[j][tt] *= a1[tt]; }
    }
    // PV: rows 32rw..+32 x cols 256cw..+256
    bf16x8 p0 = *(const bf16x8*)&Pl[(32 * rw + r) * 40 + quad * 8];
    bf16x8 p1 = *(const bf16x8*)&Pl[(32 * rw + 16 + r) * 40 + quad * 8];
#pragma unroll
    for (int j = 0; j < 16; ++j) {
      bf16x8 bv = *(const bf16x8*)&Vs[(256 * cw + 16 * j + r) * 40 + quad * 8];
      o0[j] = __builtin_amdgcn_mfma_f32_16x16x32_bf16(p0, bv, o0[j], 0, 0, 0);
      o1[j] = __builtin_amdgcn_mfma_f32_16x16x32_bf16(p1, bv, o1[j], 0, 0, 0);
    }
  }
  // epilogue
  if (quad == 0) linvL[16 * wave + r] = 1.0f / l_run;
  __syncthreads();
  f32x4 li0 = *(const f32x4*)&linvL[32 * rw + quad * 4];
  f32x4 li1 = *(const f32x4*)&linvL[32 * rw + 16 + quad * 4];
#pragma unroll
  for (int tt = 0; tt < 4; ++tt) {
    long row0 = (long)(s0 + 32 * rw + quad * 4 + tt);
    long row1 = row0 + 16;
    bf16* orow0 = Oc + (row0 * H_ + h) * KVR_ + 256 * cw;
    bf16* orow1 = Oc + (row1 * H_ + h) * KVR_ + 256 * cw;
#pragma unroll
    for (int j = 0; j < 16; ++j) {
      orow0[j * 16 + r] = tobf(o0[j][tt] * li0[tt]);
      orow1[j * 16 + r] = tobf(o1[j][tt] * li1[tt]);
    }
  }
}

extern "C" void kernel_launch(void* const* d_in, const int* in_sizes, int n_in,
                              void* d_out, int out_size, void* d_ws, size_t ws_size,
                              hipStream_t stream) {
  (void)in_sizes; (void)n_in; (void)out_size; (void)ws_size;
  const float* x     = (const float*)d_in[0];
  const float* wq    = (const float*)d_in[1];
  const float* wkv_a = (const float*)d_in[2];
  const float* kvw   = (const float*)d_in[3];
  const float* wkv_b = (const float*)d_in[4];
  const float* wo    = (const float*)d_in[5];
  const float* fcos  = (const float*)d_in[6];
  const float* fsin  = (const float*)d_in[7];
  float* out = (float*)d_out;

  char* p = (char*)d_ws;
  auto alloc = [&](size_t bytes) { char* q = p; p += (bytes + 255) & ~(size_t)255; return q; };
  const long MR = (long)B_ * S_;
  bf16* xb   = (bf16*)alloc(MR * D_ * 2);
  bf16* out2 = (bf16*)alloc(MR * D_ * 2);
  bf16* wqb  = (bf16*)alloc((long)H_ * QK_ * D_ * 2);
  bf16* wab  = (bf16*)alloc((long)KD_ * D_ * 2);
  bf16* wob  = (bf16*)alloc((long)D_ * D_ * 2);
  bf16* wbnT = (bf16*)alloc((long)H_ * KVR_ * NOPE_ * 2);
  bf16* wbv  = (bf16*)alloc((long)H_ * V_ * KVR_ * 2);
  float* kvf = (float*)alloc((long)S_ * KD_ * 4);
  bf16* keff = (bf16*)alloc((long)S_ * KD_ * 2);
  bf16* kvcT = (bf16*)alloc((long)KVR_ * S_ * 2);
  bf16* qb   = (bf16*)alloc((long)S_ * H_ * QK_ * 2);
  bf16* qeff = (bf16*)alloc((long)S_ * H_ * KD_ * 2);
  bf16* oc   = (bf16*)alloc((long)S_ * H_ * KVR_ * 2);

  cast_bf16<<<(MR * D_) >> 11, 256, 0, stream>>>(x, xb, MR * D_);
  cast_bf16<<<((long)H_ * QK_ * D_) >> 11, 256, 0, stream>>>(wq, wqb, (long)H_ * QK_ * D_);
  cast_bf16<<<((long)KD_ * D_) >> 11, 256, 0, stream>>>(wkv_a, wab, (long)KD_ * D_);
  cast_bf16<<<((long)D_ * D_) >> 11, 256, 0, stream>>>(wo, wob, (long)D_ * D_);
  prep_wkvb<<<4096, 256, 0, stream>>>(wkv_b, wbnT, wbv);

  for (int b = 0; b < B_; ++b) {
    const bf16* xb_b = xb + (long)b * S_ * D_;
    bf16* out2_b = out2 + (long)b * S_ * D_;
    gemm_bt<float><<<dim3(5, 16, 1), 256, 0, stream>>>(xb_b, D_, 0, wab, D_, 0,
                                                       kvf, KD_, 0, S_, KD_, D_);
    kv_norm<<<S_ / 4, 256, 0, stream>>>(kvf, kvw, fcos, fsin, keff);
    transpose_kvc<<<dim3(S_ / 32, KVR_ / 32, 1), 256, 0, stream>>>(keff, kvcT);
    gemm_bt<bf16><<<dim3(24, 16, 1), 256, 0, stream>>>(xb_b, D_, 0, wqb, D_, 0,
                                                       qb, H_ * QK_, 0, S_, H_ * QK_, D_);
    rope_q<<<(S_ * H_ * 32) / 256, 256, 0, stream>>>(qb, fcos, fsin, qeff);
    gemm_bt<bf16><<<dim3(4, 16, H_), 256, 0, stream>>>(qb, H_ * QK_, QK_,
                                                       wbnT, NOPE_, (long)KVR_ * NOPE_,
                                                       qeff, H_ * KD_, KD_, S_, KVR_, NOPE_);
    flash_mla<<<dim3(256), 512, 0, stream>>>(qeff, keff, kvcT, oc);
    gemm_bt<bf16><<<dim3(1, 16, H_), 256, 0, stream>>>(oc, H_ * KVR_, KVR_,
                                                       wbv, KVR_, (long)V_ * KVR_,
                                                       out2_b, D_, V_, S_, V_, KVR_);
  }
  gemm_bt<float><<<dim3(16, 64, 1), 256, 0, stream>>>(out2, D_, 0, wob, D_, 0,
                                                      out, D_, 0, MR, D_, D_);
}